// Round 5
// baseline (384.482 us; speedup 1.0000x reference)
//
#include <hip/hip_runtime.h>

#define N_NODES 131072
#define D 128
#define NLAYERS 4
#define VOCAB 320

typedef _Float16 f16;
typedef _Float16 f16x8 __attribute__((ext_vector_type(8)));
typedef float f32x4 __attribute__((ext_vector_type(4)));
typedef unsigned int u32;

// async 16B global->LDS DMA (lane-contiguous LDS dest, per-lane global src)
__device__ __forceinline__ void lds_dma16(f16* lds, const f16* g) {
    __builtin_amdgcn_global_load_lds(
        (const __attribute__((address_space(1))) u32*)(const void*)g,
        (__attribute__((address_space(3))) u32*)(void*)lds, 16, 0, 0);
}

// ---------- prep: W0t[l][n][k]=f16(W0[l][k][n]), W1t likewise; zero feat pad rows ----------
__global__ __launch_bounds__(256) void prep_weights(
    const float* __restrict__ W0, const float* __restrict__ W1,
    f16* __restrict__ W0t, f16* __restrict__ W1t,
    f16* __restrict__ fa, f16* __restrict__ fb)
{
    __shared__ float T[64][65];
    int b = blockIdx.x;
    const int tid = threadIdx.x;
    if (b == 80) {                      // zero padding row (id N_NODES) of both feat buffers
        if (tid < 32) {
            f16x8 z = {0, 0, 0, 0, 0, 0, 0, 0};
            f16* base = (tid >> 4) ? fb : fa;
            *(f16x8*)&base[(size_t)N_NODES * D + (tid & 15) * 8] = z;
        }
        return;
    }
    const float* src; f16* dst; int K, tk, tn;
    if (b < 64) {                       // W0: 4 layers x (8 k-tiles x 2 n-tiles)
        int l = b >> 4; tk = (b >> 1) & 7; tn = b & 1;
        src = W0 + (size_t)l * 512 * 128; dst = W0t + (size_t)l * 128 * 512; K = 512;
    } else {                            // W1: 4 layers x (2 x 2)
        int bb = b - 64; int l = bb >> 2; tk = (bb >> 1) & 1; tn = bb & 1;
        src = W1 + (size_t)l * 128 * 128; dst = W1t + (size_t)l * 128 * 128; K = 128;
    }
#pragma unroll
    for (int i = 0; i < 16; ++i) {
        int u = tid + 256 * i;
        int kk = u >> 6, nn = u & 63;
        T[kk][nn] = src[(size_t)(tk * 64 + kk) * 128 + tn * 64 + nn];
    }
    __syncthreads();
#pragma unroll
    for (int i = 0; i < 16; ++i) {
        int u = tid + 256 * i;
        int nn = u >> 6, kk = u & 63;
        dst[(size_t)(tn * 64 + nn) * K + tk * 64 + kk] = (f16)T[kk][nn];
    }
}

// ---------- prep: embP[t] = f16(emb[t]); embP[VOCAB] = 0 ----------
__global__ __launch_bounds__(256) void prep_emb(
    const float* __restrict__ emb, f16* __restrict__ embP)
{
    const int tid = threadIdx.x;
    if (blockIdx.x == 40) {
        if (tid < 16) {
            f16x8 z = {0, 0, 0, 0, 0, 0, 0, 0};
            *(f16x8*)&embP[(size_t)VOCAB * D + tid * 8] = z;
        }
        return;
    }
    int i = blockIdx.x * 256 + tid;     // VOCAB*32 float4 groups
    int t = i >> 5, c = i & 31;
    float4 x = ((const float4*)emb)[(size_t)t * 32 + c];
    f16 y0 = (f16)x.x, y1 = (f16)x.y, y2 = (f16)x.z, y3 = (f16)x.w;
    f16 v[4] = {y0, y1, y2, y3};
    *(unsigned long long*)&embP[(size_t)t * D + c * 4] = *(unsigned long long*)v;
}

// ---------- prep: nbr_tok[v][e] = node_idx[neighbors[v][e]] (pad -> VOCAB) ----------
__global__ __launch_bounds__(256) void prep_nbrtok(
    const int* __restrict__ node_idx, const int* __restrict__ neighbors,
    int* __restrict__ nbr_tok)
{
    int i = blockIdx.x * 256 + threadIdx.x;   // N*4
    int nbr = neighbors[i];
    nbr_tok[i] = (nbr < N_NODES) ? node_idx[nbr] : VOCAB;
}

// MFMA over one K=128 stage: B frags direct from global (L2-hot), A from swizzled LDS.
// Includes the pre-compute __syncthreads (drains the As DMA / scatter writes).
#define MFMA_STAGE(ACC, WP, WSTRIDE)                                          \
    {                                                                         \
        f16x8 bfc[4], bfn[4];                                                 \
        _Pragma("unroll")                                                     \
        for (int c = 0; c < 4; ++c)                                           \
            bfc[c] = *(const f16x8*)&(WP)[(size_t)(wc*64 + c*16 + lm) * (WSTRIDE) + quad*8]; \
        __syncthreads();                                                      \
        _Pragma("unroll")                                                     \
        for (int t = 0; t < 4; ++t) {                                         \
            if (t < 3) {                                                      \
                _Pragma("unroll")                                             \
                for (int c = 0; c < 4; ++c)                                   \
                    bfn[c] = *(const f16x8*)&(WP)[(size_t)(wc*64 + c*16 + lm) * (WSTRIDE) + (t+1)*32 + quad*8]; \
            }                                                                 \
            f16x8 af[4];                                                      \
            _Pragma("unroll")                                                 \
            for (int r = 0; r < 4; ++r) {                                     \
                int row = wr*64 + r*16 + lm;                                  \
                af[r] = *(const f16x8*)&As[row*128 + (((4*t + quad) ^ (lm & 7)) * 8)]; \
            }                                                                 \
            _Pragma("unroll")                                                 \
            for (int r = 0; r < 4; ++r)                                       \
                _Pragma("unroll")                                             \
                for (int c = 0; c < 4; ++c)                                   \
                    ACC[r][c] = __builtin_amdgcn_mfma_f32_16x16x32_f16(af[r], bfc[c], ACC[r][c], 0, 0, 0); \
            _Pragma("unroll")                                                 \
            for (int c = 0; c < 4; ++c) bfc[c] = bfn[c];                      \
        }                                                                     \
    }

// ---------- unified fused layer: h=relu(gather(fin)@W0+b0); fout=h@W1+b1 ----------
// layer 0: fin=embP, nbrtab=nbr_tok; layers 1..3: fin=feats, nbrtab=neighbors.
__global__ __launch_bounds__(256, 4) void layer_fused(
    const f16* __restrict__ fin, f16* __restrict__ fout,
    const int* __restrict__ nbrtab,
    const f16* __restrict__ W0t, const float* __restrict__ b0,
    const f16* __restrict__ W1t, const float* __restrict__ b1)
{
    __shared__ f16 As[128 * 128];       // 32 KB, XOR-swizzled 16B blocks
    __shared__ int nbr_s[512];

    const int tid  = threadIdx.x;
    const int bm   = blockIdx.x * 128;
    const int lane = tid & 63;
    const int wave = tid >> 6;
    const int wr = wave >> 1, wc = wave & 1;     // 2x2 wave grid, 64x64 tiles
    const int quad = lane >> 4, lm = lane & 15;
    const int seg  = tid & 15;                   // 16B block within a row
    const int r0   = tid >> 4;                   // 0..15
    const int kb   = seg ^ (r0 & 7);             // swizzled block this thread DMAs/stores

    nbr_s[tid]       = nbrtab[bm * 4 + tid];
    nbr_s[tid + 256] = nbrtab[bm * 4 + 256 + tid];
    __syncthreads();                             // nbr_s ready

    int rn[8];
#pragma unroll
    for (int i = 0; i < 8; ++i) rn[i] = nbr_s[(r0 + 16 * i) * 4];

    f32x4 acc1[4][4];
#pragma unroll
    for (int r = 0; r < 4; ++r)
#pragma unroll
        for (int c = 0; c < 4; ++c) acc1[r][c] = (f32x4){0.f, 0.f, 0.f, 0.f};

    // ---------------- phase 1: 4 stages of K=128 (one neighbor slot each) ----
#pragma unroll 1
    for (int e = 0; e < 4; ++e) {
        // fire-and-forget gather DMA for stage e (rows land lane-contiguous)
#pragma unroll
        for (int i = 0; i < 8; ++i)
            lds_dma16(&As[(4 * wave + 16 * i) * 128],
                      fin + (size_t)rn[i] * D + kb * 8);
        if (e < 3) {                             // preload next-stage neighbor ids
#pragma unroll
            for (int i = 0; i < 8; ++i) rn[i] = nbr_s[(r0 + 16 * i) * 4 + e + 1];
        }
        MFMA_STAGE(acc1, W0t + (size_t)e * 128, 512)
        __syncthreads();                         // As consumed, safe to overwrite
    }

    // bias + relu -> h packed to f16 pairs
    unsigned int hpk[4][4][2];
#pragma unroll
    for (int c = 0; c < 4; ++c) {
        float b0v = b0[wc * 64 + c * 16 + lm];
#pragma unroll
        for (int r = 0; r < 4; ++r)
#pragma unroll
            for (int p = 0; p < 2; ++p) {
                float v0 = fmaxf(acc1[r][c][2 * p]     + b0v, 0.f);
                float v1 = fmaxf(acc1[r][c][2 * p + 1] + b0v, 0.f);
                unsigned short u0 = __builtin_bit_cast(unsigned short, (f16)v0);
                unsigned short u1 = __builtin_bit_cast(unsigned short, (f16)v1);
                hpk[r][c][p] = ((u32)u1 << 16) | u0;
            }
    }

    // scatter h (C-layout) into swizzled As as phase-2 A operand
#pragma unroll
    for (int r = 0; r < 4; ++r)
#pragma unroll
        for (int c = 0; c < 4; ++c) {
            int gcol = wc * 64 + c * 16 + lm;
            int blk = gcol >> 3, el = gcol & 7;
#pragma unroll
            for (int reg = 0; reg < 4; ++reg) {
                int grow = wr * 64 + r * 16 + quad * 4 + reg;
                unsigned pk = hpk[r][c][reg >> 1];
                unsigned short bits = (reg & 1) ? (unsigned short)(pk >> 16)
                                                : (unsigned short)(pk & 0xffff);
                As[grow * 128 + ((blk ^ (grow & 7)) * 8) + el] =
                    __builtin_bit_cast(f16, bits);
            }
        }

    // ---------------- phase 2: fout_tile = h @ W1t, K = 128 ----------------
    f32x4 acc2[4][4];
#pragma unroll
    for (int r = 0; r < 4; ++r)
#pragma unroll
        for (int c = 0; c < 4; ++c) acc2[r][c] = (f32x4){0.f, 0.f, 0.f, 0.f};

    MFMA_STAGE(acc2, W1t, 128)                   // barrier inside covers the scatter
    __syncthreads();                             // As reads done; reuse for epilogue

    // epilogue: bias, scatter to swizzled As, then coalesced 16B stores
#pragma unroll
    for (int r = 0; r < 4; ++r)
#pragma unroll
        for (int c = 0; c < 4; ++c) {
            float b1v = b1[wc * 64 + c * 16 + lm];
            int gcol = wc * 64 + c * 16 + lm;
            int blk = gcol >> 3, el = gcol & 7;
#pragma unroll
            for (int reg = 0; reg < 4; ++reg) {
                int grow = wr * 64 + r * 16 + quad * 4 + reg;
                As[grow * 128 + ((blk ^ (grow & 7)) * 8) + el] =
                    (f16)(acc2[r][c][reg] + b1v);
            }
        }
    __syncthreads();
#pragma unroll
    for (int i = 0; i < 8; ++i) {
        int row = r0 + 16 * i;
        *(f16x8*)&fout[(size_t)(bm + row) * D + seg * 8] =
            *(const f16x8*)&As[row * 128 + kb * 8];
    }
}

// ---------- readout: per-segment mean + pairwise dot ----------
__global__ __launch_bounds__(256) void readout_f16(
    const f16* __restrict__ feats, const float* __restrict__ out_bias,
    float* __restrict__ logits)
{
    __shared__ float ms[2][128];
    const int b   = blockIdx.x;
    const int tid = threadIdx.x;
    const int side = tid >> 7, d = tid & 127;

    const f16* base = feats + ((size_t)b * 128 + side * 64) * D + d;
    float s = 0.f;
#pragma unroll 8
    for (int n = 0; n < 64; ++n) s += (float)base[(size_t)n * D];
    ms[side][d] = s * (1.0f / 64.0f);
    __syncthreads();

    if (tid < 64) {
        float v = ms[0][tid] * ms[1][tid] + ms[0][tid + 64] * ms[1][tid + 64];
#pragma unroll
        for (int off = 32; off; off >>= 1) v += __shfl_down(v, off);
        if (tid == 0) logits[b] = v + out_bias[0];
    }
}

extern "C" void kernel_launch(void* const* d_in, const int* in_sizes, int n_in,
                              void* d_out, int out_size, void* d_ws, size_t ws_size,
                              hipStream_t stream) {
    const int*   node_idx  = (const int*)d_in[0];
    const int*   neighbors = (const int*)d_in[1];
    const float* emb       = (const float*)d_in[3];
    const float* W0        = (const float*)d_in[4];
    const float* b0        = (const float*)d_in[5];
    const float* W1        = (const float*)d_in[6];
    const float* b1        = (const float*)d_in[7];
    const float* out_bias  = (const float*)d_in[8];
    float*       logits    = (float*)d_out;

    const size_t NP1 = (size_t)N_NODES + 1;                  // +1 zero pad row
    f16* feats_a = (f16*)d_ws;                               // ~33.6 MB
    f16* feats_b = feats_a + NP1 * D;                        // ~33.6 MB
    f16* W0t     = feats_b + NP1 * D;                        // 512 KB
    f16* W1t     = W0t + (size_t)NLAYERS * 512 * 128;        // 128 KB
    f16* embP    = W1t + (size_t)NLAYERS * 128 * 128;        // ~82 KB
    int* nbr_tok = (int*)(embP + (size_t)(VOCAB + 1) * D);   // 2 MB

    prep_weights<<<81, 256, 0, stream>>>(W0, W1, W0t, W1t, feats_a, feats_b);
    prep_emb<<<41, 256, 0, stream>>>(emb, embP);
    prep_nbrtok<<<N_NODES * 4 / 256, 256, 0, stream>>>(node_idx, neighbors, nbr_tok);

    // layer 0: gather from L2-resident embP via nbr_tok
    layer_fused<<<N_NODES / 128, 256, 0, stream>>>(
        embP, feats_a, nbr_tok, W0t, b0, W1t, b1);

    // layers 1..3: a->b->a->b
    f16* fin = feats_a; f16* fout = feats_b;
    for (int l = 1; l < NLAYERS; ++l) {
        layer_fused<<<N_NODES / 128, 256, 0, stream>>>(
            fin, fout, neighbors,
            W0t + (size_t)l * 512 * 128, b0 + (size_t)l * 128,
            W1t + (size_t)l * 128 * 128, b1 + (size_t)l * 128);
        f16* t = fin; fin = fout; fout = t;
    }
    readout_f16<<<N_NODES / 128, 256, 0, stream>>>(feats_b, out_bias, logits);
}

// Round 6
// 309.803 us; speedup vs baseline: 1.2411x; 1.2411x over previous
//
#include <hip/hip_runtime.h>

#define N_NODES 131072
#define D 128
#define NLAYERS 4
#define VOCAB 320

typedef _Float16 f16;
typedef _Float16 f16x8 __attribute__((ext_vector_type(8)));
typedef float f32x4 __attribute__((ext_vector_type(4)));
typedef unsigned int u32;

// ---------- prep: fragment-ordered f16 weights + zero pad rows ----------
// W0f layout: frag(e,t,g,quad,lm,j) at ((e*4+t)*8+g)*512 + quad*128 + lm*8 + j
//   (k = e*128+t*32+quad*8+j, n = g*16+lm) -> lane (quad,lm) reads base+lane*16B.
__global__ __launch_bounds__(256) void prep_wf(
    const float* __restrict__ W0, const float* __restrict__ W1,
    f16* __restrict__ W0f, f16* __restrict__ W1f,
    f16* __restrict__ fa, f16* __restrict__ fb)
{
    const int b = blockIdx.x, tid = threadIdx.x;
    if (b == 1280) {                    // zero pad row (id N_NODES) of both feat buffers
        if (tid < 32) {
            f16x8 z = {0, 0, 0, 0, 0, 0, 0, 0};
            f16* base = (tid >> 4) ? fb : fa;
            *(f16x8*)&base[(size_t)N_NODES * D + (tid & 15) * 8] = z;
        }
        return;
    }
    if (b < 1024) {                     // W0: 4 layers x 512 x 128
        int i = b * 256 + tid;
        int l = i >> 16, r = i & 65535;
        int k = r >> 7, n = r & 127;
        int e = k >> 7, t = (k >> 5) & 3, q = (k >> 3) & 3, j = k & 7;
        int g = n >> 4, lm = n & 15;
        int o = ((e * 4 + t) * 8 + g) * 512 + q * 128 + lm * 8 + j;
        W0f[(size_t)l * 65536 + o] = (f16)W0[i];
    } else {                            // W1: 4 layers x 128 x 128
        int i = (b - 1024) * 256 + tid;
        int l = i >> 14, r = i & 16383;
        int k = r >> 7, n = r & 127;
        int t = k >> 5, q = (k >> 3) & 3, j = k & 7;
        int g = n >> 4, lm = n & 15;
        int o = (t * 8 + g) * 512 + q * 128 + lm * 8 + j;
        W1f[(size_t)l * 16384 + o] = (f16)W1[i];
    }
}

// ---------- prep: embP[t] = f16(emb[t]); embP[VOCAB] = 0 ----------
__global__ __launch_bounds__(256) void prep_emb(
    const float* __restrict__ emb, f16* __restrict__ embP)
{
    const int tid = threadIdx.x;
    if (blockIdx.x == 40) {
        if (tid < 16) {
            f16x8 z = {0, 0, 0, 0, 0, 0, 0, 0};
            *(f16x8*)&embP[(size_t)VOCAB * D + tid * 8] = z;
        }
        return;
    }
    int i = blockIdx.x * 256 + tid;
    int t = i >> 5, c = i & 31;
    float4 x = ((const float4*)emb)[(size_t)t * 32 + c];
    f16 v[4] = {(f16)x.x, (f16)x.y, (f16)x.z, (f16)x.w};
    *(unsigned long long*)&embP[(size_t)t * D + c * 4] = *(unsigned long long*)v;
}

// ---------- prep: nbr_tok[v][e] = node_idx[neighbors[v][e]] (pad -> VOCAB) ----------
__global__ __launch_bounds__(256) void prep_nbrtok(
    const int* __restrict__ node_idx, const int* __restrict__ neighbors,
    int* __restrict__ nbr_tok)
{
    int i = blockIdx.x * 256 + threadIdx.x;
    int nbr = neighbors[i];
    nbr_tok[i] = (nbr < N_NODES) ? node_idx[nbr] : VOCAB;
}

// ---------- fused layer: h=relu(gather(fin)@W0+b0); fout=h@W1+b1 ----------
// Phase 1 is barrier-free: A-fragments gathered straight into registers
// (lane(quad,lm) = 16B of row nbr(lm)), B-fragments from fragment-ordered
// weights (coalesced lane*16B). Double-buffered frags = 1-iter prefetch.
__global__ __launch_bounds__(256, 3) void layer_fused(
    const f16* __restrict__ fin, f16* __restrict__ fout,
    const int* __restrict__ nbrtab,
    const f16* __restrict__ W0f, const float* __restrict__ b0,
    const f16* __restrict__ W1f, const float* __restrict__ b1)
{
    __shared__ f16 As[128 * 128];       // 32 KB, phase-2 h transform only
    __shared__ int nbr_s[512];

    const int tid  = threadIdx.x;
    const int bm   = blockIdx.x * 128;
    const int lane = tid & 63;
    const int wave = tid >> 6;
    const int wr = wave >> 1, wc = wave & 1;     // 2x2 wave grid, 64x64 tiles
    const int quad = lane >> 4, lm = lane & 15;

    nbr_s[tid]       = nbrtab[bm * 4 + tid];
    nbr_s[tid + 256] = nbrtab[bm * 4 + 256 + tid];
    __syncthreads();

    const int rbase = (wr * 64 + lm) * 4;        // nbr_s[(wr*64 + r*16 + lm)*4 + e]

    f32x4 acc1[4][4];
#pragma unroll
    for (int r = 0; r < 4; ++r)
#pragma unroll
        for (int c = 0; c < 4; ++c) acc1[r][c] = (f32x4){0.f, 0.f, 0.f, 0.f};

    int   rn[2][4];
    f16x8 af[2][4], bf[2][4];

#pragma unroll
    for (int r = 0; r < 4; ++r) rn[0][r] = nbr_s[rbase + r * 64];
#pragma unroll
    for (int r = 0; r < 4; ++r)
        af[0][r] = *(const f16x8*)&fin[(size_t)rn[0][r] * D + quad * 8];
#pragma unroll
    for (int c = 0; c < 4; ++c)
        bf[0][c] = *(const f16x8*)&W0f[(size_t)(wc * 4 + c) * 512 + lane * 8];

    // ---- phase 1: K=512 as 16 frag-steps (e=slot 0..3, t=k-chunk 0..3) ----
#pragma unroll
    for (int et = 0; et < 16; ++et) {
        const int cur = et & 1, nxt = cur ^ 1;
        if (et < 15) {
            const int en = (et + 1) >> 2, tn = (et + 1) & 3;
            if (tn == 0) {
#pragma unroll
                for (int r = 0; r < 4; ++r) rn[nxt][r] = nbr_s[rbase + r * 64 + en];
            } else {
#pragma unroll
                for (int r = 0; r < 4; ++r) rn[nxt][r] = rn[cur][r];
            }
#pragma unroll
            for (int r = 0; r < 4; ++r)
                af[nxt][r] = *(const f16x8*)&fin[(size_t)rn[nxt][r] * D + tn * 32 + quad * 8];
#pragma unroll
            for (int c = 0; c < 4; ++c)
                bf[nxt][c] = *(const f16x8*)&W0f[(size_t)((en * 4 + tn) * 8 + wc * 4 + c) * 512 + lane * 8];
        }
#pragma unroll
        for (int r = 0; r < 4; ++r)
#pragma unroll
            for (int c = 0; c < 4; ++c)
                acc1[r][c] = __builtin_amdgcn_mfma_f32_16x16x32_f16(
                    af[cur][r], bf[cur][c], acc1[r][c], 0, 0, 0);
    }

    // ---- bias + relu -> h packed f16 pairs ----
    unsigned int hpk[4][4][2];
#pragma unroll
    for (int c = 0; c < 4; ++c) {
        float b0v = b0[wc * 64 + c * 16 + lm];
#pragma unroll
        for (int r = 0; r < 4; ++r)
#pragma unroll
            for (int p = 0; p < 2; ++p) {
                float v0 = fmaxf(acc1[r][c][2 * p]     + b0v, 0.f);
                float v1 = fmaxf(acc1[r][c][2 * p + 1] + b0v, 0.f);
                unsigned short u0 = __builtin_bit_cast(unsigned short, (f16)v0);
                unsigned short u1 = __builtin_bit_cast(unsigned short, (f16)v1);
                hpk[r][c][p] = ((u32)u1 << 16) | u0;
            }
    }

    // ---- scatter h (C-layout) into XOR-swizzled As as phase-2 A operand ----
#pragma unroll
    for (int r = 0; r < 4; ++r)
#pragma unroll
        for (int c = 0; c < 4; ++c) {
            int gcol = wc * 64 + c * 16 + lm;
            int blk = gcol >> 3, el = gcol & 7;
#pragma unroll
            for (int reg = 0; reg < 4; ++reg) {
                int grow = wr * 64 + r * 16 + quad * 4 + reg;
                unsigned pk = hpk[r][c][reg >> 1];
                unsigned short bits = (reg & 1) ? (unsigned short)(pk >> 16)
                                                : (unsigned short)(pk & 0xffff);
                As[grow * 128 + ((blk ^ (grow & 7)) * 8) + el] =
                    __builtin_bit_cast(f16, bits);
            }
        }

    // preload phase-2 B frags (t=0) while waiting
    f16x8 pbf[2][4];
#pragma unroll
    for (int c = 0; c < 4; ++c)
        pbf[0][c] = *(const f16x8*)&W1f[(size_t)(wc * 4 + c) * 512 + lane * 8];
    __syncthreads();                              // h scatter visible

    // ---- phase 2: fout_tile = h @ W1, K=128 ----
    f32x4 acc2[4][4];
#pragma unroll
    for (int r = 0; r < 4; ++r)
#pragma unroll
        for (int c = 0; c < 4; ++c) acc2[r][c] = (f32x4){0.f, 0.f, 0.f, 0.f};

#pragma unroll
    for (int t = 0; t < 4; ++t) {
        const int cur = t & 1, nxt = cur ^ 1;
        if (t < 3) {
#pragma unroll
            for (int c = 0; c < 4; ++c)
                pbf[nxt][c] = *(const f16x8*)&W1f[(size_t)((t + 1) * 8 + wc * 4 + c) * 512 + lane * 8];
        }
        f16x8 a2[4];
#pragma unroll
        for (int r = 0; r < 4; ++r) {
            int row = wr * 64 + r * 16 + lm;
            a2[r] = *(const f16x8*)&As[row * 128 + (((4 * t + quad) ^ (lm & 7)) * 8)];
        }
#pragma unroll
        for (int r = 0; r < 4; ++r)
#pragma unroll
            for (int c = 0; c < 4; ++c)
                acc2[r][c] = __builtin_amdgcn_mfma_f32_16x16x32_f16(
                    a2[r], pbf[cur][c], acc2[r][c], 0, 0, 0);
    }
    __syncthreads();                              // As reads done; reuse for epilogue

    // ---- epilogue: bias, scatter to swizzled As, coalesced 16B stores ----
#pragma unroll
    for (int r = 0; r < 4; ++r)
#pragma unroll
        for (int c = 0; c < 4; ++c) {
            float b1v = b1[wc * 64 + c * 16 + lm];
            int gcol = wc * 64 + c * 16 + lm;
            int blk = gcol >> 3, el = gcol & 7;
#pragma unroll
            for (int reg = 0; reg < 4; ++reg) {
                int grow = wr * 64 + r * 16 + quad * 4 + reg;
                As[grow * 128 + ((blk ^ (grow & 7)) * 8) + el] =
                    (f16)(acc2[r][c][reg] + b1v);
            }
        }
    __syncthreads();
    {
        const int seg = tid & 15, r0 = tid >> 4;
        const int kb  = seg ^ (r0 & 7);
#pragma unroll
        for (int i = 0; i < 8; ++i) {
            int row = r0 + 16 * i;
            *(f16x8*)&fout[(size_t)(bm + row) * D + seg * 8] =
                *(const f16x8*)&As[row * 128 + kb * 8];
        }
    }
}

// ---------- readout: per-segment mean + pairwise dot ----------
__global__ __launch_bounds__(256) void readout_f16(
    const f16* __restrict__ feats, const float* __restrict__ out_bias,
    float* __restrict__ logits)
{
    __shared__ float ms[2][128];
    const int b   = blockIdx.x;
    const int tid = threadIdx.x;
    const int side = tid >> 7, d = tid & 127;

    const f16* base = feats + ((size_t)b * 128 + side * 64) * D + d;
    float s = 0.f;
#pragma unroll 8
    for (int n = 0; n < 64; ++n) s += (float)base[(size_t)n * D];
    ms[side][d] = s * (1.0f / 64.0f);
    __syncthreads();

    if (tid < 64) {
        float v = ms[0][tid] * ms[1][tid] + ms[0][tid + 64] * ms[1][tid + 64];
#pragma unroll
        for (int off = 32; off; off >>= 1) v += __shfl_down(v, off);
        if (tid == 0) logits[b] = v + out_bias[0];
    }
}

extern "C" void kernel_launch(void* const* d_in, const int* in_sizes, int n_in,
                              void* d_out, int out_size, void* d_ws, size_t ws_size,
                              hipStream_t stream) {
    const int*   node_idx  = (const int*)d_in[0];
    const int*   neighbors = (const int*)d_in[1];
    const float* emb       = (const float*)d_in[3];
    const float* W0        = (const float*)d_in[4];
    const float* b0        = (const float*)d_in[5];
    const float* W1        = (const float*)d_in[6];
    const float* b1        = (const float*)d_in[7];
    const float* out_bias  = (const float*)d_in[8];
    float*       logits    = (float*)d_out;

    const size_t NP1 = (size_t)N_NODES + 1;                  // +1 zero pad row
    f16* feats_a = (f16*)d_ws;                               // ~33.6 MB
    f16* feats_b = feats_a + NP1 * D;                        // ~33.6 MB
    f16* W0f     = feats_b + NP1 * D;                        // 512 KB
    f16* W1f     = W0f + (size_t)NLAYERS * 512 * 128;        // 128 KB
    f16* embP    = W1f + (size_t)NLAYERS * 128 * 128;        // ~82 KB
    int* nbr_tok = (int*)(embP + (size_t)(VOCAB + 1) * D);   // 2 MB

    prep_wf<<<1281, 256, 0, stream>>>(W0, W1, W0f, W1f, feats_a, feats_b);
    prep_emb<<<41, 256, 0, stream>>>(emb, embP);
    prep_nbrtok<<<N_NODES * 4 / 256, 256, 0, stream>>>(node_idx, neighbors, nbr_tok);

    // layer 0: gather from L2-resident embP via nbr_tok
    layer_fused<<<N_NODES / 128, 256, 0, stream>>>(
        embP, feats_a, nbr_tok, W0f, b0, W1f, b1);

    // layers 1..3: a->b->a->b
    f16* fin = feats_a; f16* fout = feats_b;
    for (int l = 1; l < NLAYERS; ++l) {
        layer_fused<<<N_NODES / 128, 256, 0, stream>>>(
            fin, fout, neighbors,
            W0f + (size_t)l * 512 * 128, b0 + (size_t)l * 128,
            W1f + (size_t)l * 128 * 128, b1 + (size_t)l * 128);
        f16* t = fin; fin = fout; fout = t;
    }
    readout_f16<<<N_NODES / 128, 256, 0, stream>>>(feats_b, out_bias, logits);
}